// Round 2
// baseline (422.595 us; speedup 1.0000x reference)
//
#include <hip/hip_runtime.h>
#include <stdint.h>

// Problem: out[b][o] = clamp((sum_k x[b][k]*W[o][k] + t[o]) >> (-n[o]), act_min[o], act_max[o])
// B=8192, IN=4096, OUT=4096. x,W arrive as int32 arrays (values in [-128,127]).
// Output buffer is read by the harness as int32 (int8 reference output -> 'int32' path).

#define BDIM 8192
#define INDIM 4096
#define OUTDIM 4096

typedef __attribute__((ext_vector_type(4))) int I4;

// ---------------- pack: int32 -> int8 ----------------
__global__ __launch_bounds__(256) void pack_i32_to_i8(const int* __restrict__ src,
                                                      uint32_t* __restrict__ dst, int n4) {
    int idx = blockIdx.x * 256 + threadIdx.x;
    if (idx >= n4) return;
    int4 a = ((const int4*)src)[idx];
    uint32_t p = ((uint32_t)a.x & 255u)
               | (((uint32_t)a.y & 255u) << 8)
               | (((uint32_t)a.z & 255u) << 16)
               | (((uint32_t)a.w & 255u) << 24);
    dst[idx] = p;
}

// ---------------- GEMM: 128x128 tile, BK=64, mfma_i32_16x16x64_i8 ----------------
// m97 structure: global_load_lds(16B) staging, 2-barrier K-loop, 4 waves,
// each wave computes a 64x64 quadrant as 4x4 grid of 16x16 MFMAs.
__global__ __launch_bounds__(256) void gemm_i8_fused(
    const uint8_t* __restrict__ Xp,   // [BDIM][INDIM] int8 packed
    const uint8_t* __restrict__ Wp,   // [OUTDIM][INDIM] int8 packed
    const int* __restrict__ t, const int* __restrict__ nsh,
    const int* __restrict__ amin, const int* __restrict__ amax,
    int* __restrict__ out) {

    __shared__ uint8_t sA[128 * 64];  // 8 KB
    __shared__ uint8_t sB[128 * 64];  // 8 KB

    const int bn = blockIdx.x;            // 0..31  (OUT tiles)
    const int bm = blockIdx.y;            // 0..63  (batch tiles)
    const int tid = threadIdx.x;
    const int w = tid >> 6;               // wave 0..3
    const int lane = tid & 63;
    const int wm = (w & 1) * 64;          // wave quadrant within 128x128
    const int wn = (w >> 1) * 64;

    // staging lane geometry: 1024B chunk per wave-instruction = 16 rows of 64B
    const int lrow = lane >> 2;           // 0..15
    const int lcol = (lane & 3) * 16;     // 0/16/32/48

    const uint8_t* gA0 = Xp + (size_t)(bm * 128) * INDIM;
    const uint8_t* gB0 = Wp + (size_t)(bn * 128) * INDIM;

    I4 acc[4][4];
#pragma unroll
    for (int i = 0; i < 4; ++i)
#pragma unroll
        for (int j = 0; j < 4; ++j) acc[i][j] = (I4){0, 0, 0, 0};

    const int quad = lane >> 4;           // 0..3
    const int rl = lane & 15;

    for (int k0 = 0; k0 < INDIM; k0 += 64) {
#pragma unroll
        for (int r = 0; r < 2; ++r) {
            const int c = r * 4 + w;              // chunk 0..7
            const int row = c * 16 + lrow;        // tile row 0..127
            __builtin_amdgcn_global_load_lds(
                (const __attribute__((address_space(1))) uint32_t*)(gA0 + (size_t)row * INDIM + k0 + lcol),
                (__attribute__((address_space(3))) uint32_t*)(sA + c * 1024 + lane * 16),
                16, 0, 0);
            __builtin_amdgcn_global_load_lds(
                (const __attribute__((address_space(1))) uint32_t*)(gB0 + (size_t)row * INDIM + k0 + lcol),
                (__attribute__((address_space(3))) uint32_t*)(sB + c * 1024 + lane * 16),
                16, 0, 0);
        }
        __syncthreads();   // drains vmcnt -> tiles ready

        I4 af[4], bf[4];
#pragma unroll
        for (int i = 0; i < 4; ++i)
            af[i] = *(const I4*)(sA + (wm + i * 16 + rl) * 64 + quad * 16);
#pragma unroll
        for (int j = 0; j < 4; ++j)
            bf[j] = *(const I4*)(sB + (wn + j * 16 + rl) * 64 + quad * 16);

#pragma unroll
        for (int i = 0; i < 4; ++i)
#pragma unroll
            for (int j = 0; j < 4; ++j)
                acc[i][j] = __builtin_amdgcn_mfma_i32_16x16x64_i8(af[i], bf[j], acc[i][j], 0, 0, 0);

        __syncthreads();   // protect LDS before next overwrite
    }

    // epilogue: C/D layout col=lane&15, row=(lane>>4)*4+reg
#pragma unroll
    for (int j = 0; j < 4; ++j) {
        const int o = bn * 128 + wn + j * 16 + rl;
        const int tt = t[o];
        const int sh = -nsh[o];
        const int mn = amin[o];
        const int mx = amax[o];
#pragma unroll
        for (int i = 0; i < 4; ++i) {
            const int rowbase = bm * 128 + wm + i * 16 + quad * 4;
#pragma unroll
            for (int r = 0; r < 4; ++r) {
                int v = acc[i][j][r] + tt;
                v >>= sh;
                v = v < mn ? mn : (v > mx ? mx : v);
                out[(size_t)(rowbase + r) * OUTDIM + o] = v;
            }
        }
    }
}

extern "C" void kernel_launch(void* const* d_in, const int* in_sizes, int n_in,
                              void* d_out, int out_size, void* d_ws, size_t ws_size,
                              hipStream_t stream) {
    const int* x = (const int*)d_in[0];       // [8192][4096]
    const int* W = (const int*)d_in[1];       // [4096][4096]
    const int* t = (const int*)d_in[2];       // [4096]
    const int* n = (const int*)d_in[3];       // [4096]
    const int* amin = (const int*)d_in[4];    // [4096]
    const int* amax = (const int*)d_in[5];    // [4096]
    int* out = (int*)d_out;

    uint8_t* xp = (uint8_t*)d_ws;                              // 33554432 B
    uint8_t* wp = xp + (size_t)BDIM * INDIM;                   // 16777216 B

    {
        int n4 = BDIM * INDIM / 4;   // 8388608
        pack_i32_to_i8<<<n4 / 256, 256, 0, stream>>>(x, (uint32_t*)xp, n4);
    }
    {
        int n4 = OUTDIM * INDIM / 4; // 4194304
        pack_i32_to_i8<<<n4 / 256, 256, 0, stream>>>(W, (uint32_t*)wp, n4);
    }

    dim3 grid(OUTDIM / 128, BDIM / 128);  // (32, 64)
    gemm_i8_fused<<<grid, 256, 0, stream>>>(xp, wp, t, n, amin, amax, out);
}